// Round 4
// baseline (170.749 us; speedup 1.0000x reference)
//
#include <hip/hip_runtime.h>
#include <math.h>

#define KW 11
#define HALO 10
#define TY 32
#define BATCH 32
#define HH 512
#define WW 512
#define OH 502
#define OW 502
#define NSX 8          // 8 strips x 64 cols = 512 (last strip: 54 valid outputs)
#define WPB 4          // independent waves per block
#define NBX 2
#define NBY 16
#define NWAVE (BATCH * NBY * NSX)
#define C3V 1.0e-4f
#define SW 80          // staged cols per row (64 + 16 halo)

// 4 independent waves/block (no __syncthreads). Each wave: 64-col strip,
// rows streamed through an 11-slot LDS ring of interleaved (a,b) float2 rows.
// Pipeline: row q global-loaded at phase q-3, ds_written at q-2, read at q.
// All LDS addresses are compile-time (slot == phase). h-conv from 12-col
// b64 window reads; vertical conv in register-rotated sliding accumulators.
__global__ __launch_bounds__(256, 4) void ssim_strip_kernel(
    const float* __restrict__ in1,
    const float* __restrict__ in2,
    const float* __restrict__ win,
    double* __restrict__ partials)
{
    __shared__ float2 sh[WPB][KW][SW];   // 28160 B

    const int t = threadIdx.x;
    const int wid = t >> 6;
    const int lane = t & 63;
    const int strip = blockIdx.x * WPB + wid;
    const int x0 = strip * 64;
    const int y0 = blockIdx.y * TY;
    const int img = blockIdx.z;

    const int nx = min(64, OW - x0);     // 64, last strip 54
    const int ny = min(TY, OH - y0);     // 32, last y-strip 22
    const int rows = ny + HALO;          // 42 or 32

    // separable 1D gaussian: w2d[i][j] = g[i]*g[j]
    float gv[KW];
    {
        const float c = sqrtf(win[5 * KW + 5]);
        #pragma unroll
        for (int i = 0; i < KW; ++i) gv[i] = win[i * KW + 5] / c;
    }

    const float maskf = (lane < nx) ? 1.f : 0.f;

    const float* b1 = in1 + (size_t)img * HH * WW;
    const float* b2 = in2 + (size_t)img * HH * WW;
    const int mcol = x0 + lane;                   // < 512 always
    const int hcol = min(x0 + 64 + lane, WW - 1); // halo col (lane<16)
    const bool hal = lane < 16;

    float2* const mysh = &sh[wid][0][0];          // slot stride = SW float2

    // two register staging sets (parity compile-time inside the unroll)
    float sa0 = 0.f, sb0 = 0.f, ha0 = 0.f, hb0 = 0.f;
    float sa1 = 0.f, sb1 = 0.f, ha1 = 0.f, hb1 = 0.f;

    auto LOADR = [&](int q, float& A, float& B, float& HA, float& HB) {
        const int rq = min(y0 + q, HH - 1);
        const float* r1 = b1 + (size_t)rq * WW;
        const float* r2 = b2 + (size_t)rq * WW;
        A = r1[mcol];
        B = r2[mcol];
        if (hal) { HA = r1[hcol]; HB = r2[hcol]; }
    };
    auto WRITES = [&](int slot, float A, float B, float HA, float HB) {
        mysh[slot * SW + lane] = make_float2(A, B);
        if (hal) mysh[slot * SW + 64 + lane] = make_float2(HA, HB);
    };

    float acc0[KW], acc1[KW], acc2[KW], acc3[KW], acc4[KW];
    #pragma unroll
    for (int i = 0; i < KW; ++i) {
        acc0[i] = 0.f; acc1[i] = 0.f; acc2[i] = 0.f; acc3[i] = 0.f; acc4[i] = 0.f;
    }

    double tsum = 0.0;

    // prologue: rows 0,1 loaded+written; row 2 loaded into set0
    LOADR(0, sa0, sb0, ha0, hb0);
    LOADR(1, sa1, sb1, ha1, hb1);
    WRITES(0, sa0, sb0, ha0, hb0);
    WRITES(1, sa1, sb1, ha1, hb1);
    LOADR(2, sa0, sb0, ha0, hb0);

#define PHASE(p) { \
    const int yr = yrc + (p); \
    if (yr < rows) { \
        const float2* rp = mysh + (p) * SW + lane; \
        float2 w[12]; \
        _Pragma("unroll") \
        for (int j = 0; j < 12; ++j) w[j] = rp[j]; \
        if (yr + 3 < rows) { \
            if ((p) & 1) LOADR(yr + 3, sa0, sb0, ha0, hb0); \
            else         LOADR(yr + 3, sa1, sb1, ha1, hb1); \
        } \
        if (yr + 2 < rows) { \
            if ((p) & 1) WRITES(((p) + 2) % KW, sa1, sb1, ha1, hb1); \
            else         WRITES(((p) + 2) % KW, sa0, sb0, ha0, hb0); \
        } \
        float h0 = 0.f, h1 = 0.f, h2 = 0.f, h3 = 0.f, h4 = 0.f; \
        _Pragma("unroll") \
        for (int j = 0; j < KW; ++j) { \
            const float a = w[j].x, b = w[j].y; \
            const float ga = gv[j] * a, gb = gv[j] * b; \
            h0 += ga; h1 += gb; \
            h2 = fmaf(ga, a, h2); h3 = fmaf(gb, b, h3); h4 = fmaf(ga, b, h4); \
        } \
        _Pragma("unroll") \
        for (int r2 = 0; r2 < KW; ++r2) { \
            const int jj = (r2 - (p) + KW) % KW; \
            const float wv = gv[HALO - jj]; \
            acc0[r2] = fmaf(wv, h0, acc0[r2]); \
            acc1[r2] = fmaf(wv, h1, acc1[r2]); \
            acc2[r2] = fmaf(wv, h2, acc2[r2]); \
            acc3[r2] = fmaf(wv, h3, acc3[r2]); \
            acc4[r2] = fmaf(wv, h4, acc4[r2]); \
        } \
        if (yr >= HALO) { \
            const float mu1 = acc0[(p)], mu2 = acc1[(p)]; \
            const float e11 = acc2[(p)], e22 = acc3[(p)], e12 = acc4[(p)]; \
            const float s1q = fmaf(-mu1, mu1, e11); \
            const float s2q = fmaf(-mu2, mu2, e22); \
            const float s12 = fmaf(-mu1, mu2, e12); \
            const float den = __builtin_amdgcn_sqrtf(fabsf(s1q)) * \
                              __builtin_amdgcn_sqrtf(fabsf(s2q)) + C3V; \
            const float s = (s12 + C3V) * __builtin_amdgcn_rcpf(den); \
            csum = fmaf(s, maskf, csum); \
        } \
        acc0[(p)] = 0.f; acc1[(p)] = 0.f; acc2[(p)] = 0.f; \
        acc3[(p)] = 0.f; acc4[(p)] = 0.f; \
    } \
}

    int yrc = 0;
    while (yrc < rows) {
        float csum = 0.f;
        PHASE(0) PHASE(1) PHASE(2) PHASE(3) PHASE(4) PHASE(5)
        PHASE(6) PHASE(7) PHASE(8) PHASE(9) PHASE(10)
        tsum += (double)csum;
        yrc += KW;
        // chunk parity fix: swap staging sets
        { float tmp;
          tmp = sa0; sa0 = sa1; sa1 = tmp;
          tmp = sb0; sb0 = sb1; sb1 = tmp;
          tmp = ha0; ha0 = ha1; ha1 = tmp;
          tmp = hb0; hb0 = hb1; hb1 = tmp; }
    }
#undef PHASE

    // per-wave deterministic reduction
    #pragma unroll
    for (int off = 32; off > 0; off >>= 1)
        tsum += __shfl_down(tsum, off, 64);
    if (lane == 0) {
        const int bid = (img * NBY + blockIdx.y) * NSX + strip;
        partials[bid] = tsum;
    }
}

// deterministic final reduce of the 4096 wave partials -> mean
__global__ __launch_bounds__(256) void ssim_reduce_kernel(
    const double* __restrict__ partials, float* __restrict__ out)
{
    __shared__ double sred[4];
    double s = 0.0;
    for (int i = threadIdx.x; i < NWAVE; i += 256) s += partials[i];
    #pragma unroll
    for (int off = 32; off > 0; off >>= 1)
        s += __shfl_down(s, off, 64);
    const int wid = threadIdx.x >> 6;
    const int lane = threadIdx.x & 63;
    if (lane == 0) sred[wid] = s;
    __syncthreads();
    if (threadIdx.x == 0) {
        const double total = sred[0] + sred[1] + sred[2] + sred[3];
        out[0] = (float)(total / ((double)BATCH * OH * OW));
    }
}

extern "C" void kernel_launch(void* const* d_in, const int* in_sizes, int n_in,
                              void* d_out, int out_size, void* d_ws, size_t ws_size,
                              hipStream_t stream) {
    const float* in1 = (const float*)d_in[0];
    const float* in2 = (const float*)d_in[1];
    const float* win = (const float*)d_in[2];
    float* out = (float*)d_out;
    double* partials = (double*)d_ws;   // 4096 doubles = 32 KB

    dim3 grid(NBX, NBY, BATCH);
    dim3 block(WPB * 64);
    ssim_strip_kernel<<<grid, block, 0, stream>>>(in1, in2, win, partials);
    ssim_reduce_kernel<<<1, 256, 0, stream>>>(partials, out);
}

// Round 5
// 54.256 us; speedup vs baseline: 3.1471x; 3.1471x over previous
//
#include <hip/hip_runtime.h>
#include <math.h>

#define KW 11
#define HALO 10
#define TY 32
#define BATCH 32
#define HH 512
#define WW 512
#define OH 502
#define OW 502
#define NSX 8          // 8 strips x 64 cols
#define WPB 4          // independent waves per block (no __syncthreads)
#define NBX 2
#define NBY 16
#define NWAVE (BATCH * NBY * NSX)
#define C3V 1.0e-4f
#define SW 80          // staged cols per row (64 + 16 halo), float2 each

static __device__ __forceinline__ float rfl(float x) {
    return __int_as_float(__builtin_amdgcn_readfirstlane(__float_as_int(x)));
}

// 4 independent waves/block. Each wave: 64-col strip, 44 rows streamed through
// an 11-slot wave-private LDS ring of interleaved (a,b) float2 rows.
// Per phase: global-prefetch row yr+1 (regs) -> ds_read window (slot p) ->
// h-conv -> register-rotated vertical accumulators -> fused epilogue ->
// ds_write row yr+1 to slot (p+1)%11. All LDS addresses compile-time.
__global__ __launch_bounds__(256) void ssim_strip_kernel(
    const float* __restrict__ in1,
    const float* __restrict__ in2,
    const float* __restrict__ win,
    double* __restrict__ partials)
{
    __shared__ float2 sh[WPB][KW][SW];   // 28160 B

    const int t = threadIdx.x;
    const int wid = t >> 6;
    const int lane = t & 63;
    const int strip = blockIdx.x * WPB + wid;
    const int x0 = strip * 64;
    const int y0 = blockIdx.y * TY;
    const int img = blockIdx.z;

    const int nx = min(64, OW - x0);     // 64, last strip 54
    const int ny = min(TY, OH - y0);     // 32, last y-strip 22

    // separable 1D gaussian -> SGPRs: w2d[i][j] = g[i]*g[j]
    float gv[KW];
    {
        const float c = sqrtf(win[5 * KW + 5]);
        #pragma unroll
        for (int i = 0; i < KW; ++i) gv[i] = rfl(win[i * KW + 5] / c);
    }

    const float maskf = (lane < nx) ? 1.f : 0.f;
    const bool stager = lane < 40;                    // 40 lanes x 2 cols = 80
    const int scol = min(x0 + 2 * lane, WW - 2);      // clamped: no OOB ever
    const float* b1 = in1 + (size_t)img * HH * WW;
    const float* b2 = in2 + (size_t)img * HH * WW;

    float2* const mysh = &sh[wid][0][0];              // slot stride = SW float2

    float2 va, vb;
#define LOADR(q) { const int rq = min(y0 + (q), HH - 1);            \
    va = *(const float2*)(b1 + (size_t)rq * WW + scol);             \
    vb = *(const float2*)(b2 + (size_t)rq * WW + scol); }
#define WRITES(slot) { if (stager)                                   \
    *(float4*)&mysh[(slot) * SW + 2 * lane] =                        \
        make_float4(va.x, vb.x, va.y, vb.y); }

    float acc0[KW], acc1[KW], acc2[KW], acc3[KW], acc4[KW];
    #pragma unroll
    for (int i = 0; i < KW; ++i) {
        acc0[i] = 0.f; acc1[i] = 0.f; acc2[i] = 0.f; acc3[i] = 0.f; acc4[i] = 0.f;
    }

    double tsum = 0.0;

    LOADR(0);
    WRITES(0);

    for (int c = 0; c < 4; ++c) {        // 44 rows total, fixed
        float csum = 0.f;
        #pragma unroll
        for (int p = 0; p < KW; ++p) {
            const int yr = c * KW + p;
            LOADR(yr + 1);               // global prefetch (row clamped)

            // horizontal 11-tap conv, interleaved window reads (b64)
            float h0 = 0.f, h1 = 0.f, h2 = 0.f, h3 = 0.f, h4 = 0.f;
            const float2* rp = mysh + p * SW + lane;
            #pragma unroll
            for (int j = 0; j < KW; ++j) {
                const float2 ab = rp[j];
                const float a = ab.x, b = ab.y;
                const float ga = gv[j] * a, gb = gv[j] * b;
                h0 += ga; h1 += gb;
                h2 = fmaf(ga, a, h2); h3 = fmaf(gb, b, h3); h4 = fmaf(ga, b, h4);
            }
            // vertical accumulate: at phase p, slot j lives in register (j+p)%11
            #pragma unroll
            for (int r = 0; r < KW; ++r) {
                const int j = (r - p + KW) % KW;
                const float w = gv[HALO - j];
                acc0[r] = fmaf(w, h0, acc0[r]);
                acc1[r] = fmaf(w, h1, acc1[r]);
                acc2[r] = fmaf(w, h2, acc2[r]);
                acc3[r] = fmaf(w, h3, acc3[r]);
                acc4[r] = fmaf(w, h4, acc4[r]);
            }
            // register p completes -> output row yr-10 (uniform branch)
            if (yr >= HALO) {
                const float mu1 = acc0[p], mu2 = acc1[p];
                const float s1q = fmaf(-mu1, mu1, acc2[p]);
                const float s2q = fmaf(-mu2, mu2, acc3[p]);
                const float s12 = fmaf(-mu1, mu2, acc4[p]);
                const float den = __builtin_amdgcn_sqrtf(fabsf(s1q)) *
                                  __builtin_amdgcn_sqrtf(fabsf(s2q)) + C3V;
                const float s = (s12 + C3V) * __builtin_amdgcn_rcpf(den);
                const float m = ((yr - HALO) < ny) ? maskf : 0.f;
                csum = fmaf(s, m, csum);
            }
            acc0[p] = 0.f; acc1[p] = 0.f; acc2[p] = 0.f;
            acc3[p] = 0.f; acc4[p] = 0.f;

            WRITES((p + 1) % KW);        // row yr+1 -> slot p+1
        }
        tsum += (double)csum;
    }
#undef LOADR
#undef WRITES

    // per-wave deterministic reduction
    #pragma unroll
    for (int off = 32; off > 0; off >>= 1)
        tsum += __shfl_down(tsum, off, 64);
    if (lane == 0) {
        const int bid = (img * NBY + blockIdx.y) * NSX + strip;
        partials[bid] = tsum;
    }
}

// deterministic final reduce of the 4096 wave partials -> mean
__global__ __launch_bounds__(256) void ssim_reduce_kernel(
    const double* __restrict__ partials, float* __restrict__ out)
{
    __shared__ double sred[4];
    double s = 0.0;
    for (int i = threadIdx.x; i < NWAVE; i += 256) s += partials[i];
    #pragma unroll
    for (int off = 32; off > 0; off >>= 1)
        s += __shfl_down(s, off, 64);
    const int wid = threadIdx.x >> 6;
    const int lane = threadIdx.x & 63;
    if (lane == 0) sred[wid] = s;
    __syncthreads();
    if (threadIdx.x == 0) {
        const double total = sred[0] + sred[1] + sred[2] + sred[3];
        out[0] = (float)(total / ((double)BATCH * OH * OW));
    }
}

extern "C" void kernel_launch(void* const* d_in, const int* in_sizes, int n_in,
                              void* d_out, int out_size, void* d_ws, size_t ws_size,
                              hipStream_t stream) {
    const float* in1 = (const float*)d_in[0];
    const float* in2 = (const float*)d_in[1];
    const float* win = (const float*)d_in[2];
    float* out = (float*)d_out;
    double* partials = (double*)d_ws;   // 4096 doubles = 32 KB

    dim3 grid(NBX, NBY, BATCH);
    dim3 block(WPB * 64);
    ssim_strip_kernel<<<grid, block, 0, stream>>>(in1, in2, win, partials);
    ssim_reduce_kernel<<<1, 256, 0, stream>>>(partials, out);
}

// Round 6
// 48.526 us; speedup vs baseline: 3.5187x; 1.1181x over previous
//
#include <hip/hip_runtime.h>
#include <math.h>

#define KW 11
#define HALO 10
#define TY 32
#define BATCH 32
#define HH 512
#define WW 512
#define OH 502
#define OW 502
#define NSX 8          // 8 strips x 64 cols
#define WPB 4          // independent waves per block (no __syncthreads)
#define NBX 2
#define NBY 16
#define NWAVE (BATCH * NBY * NSX)
#define C3V 1.0e-4f
#define SW 80          // staged cols per row (64 + 16 halo), one v2f (a,b) each

typedef float v2f __attribute__((ext_vector_type(2)));

static __device__ __forceinline__ float rfl(float x) {
    return __int_as_float(__builtin_amdgcn_readfirstlane(__float_as_int(x)));
}

// 4 independent waves/block. Each wave: 64-col strip, 44 rows through an
// 11-slot wave-private LDS ring of interleaved (a,b) rows. Packed-f32 math:
// channels (a,b) and (aa,bb) ride v_pk_fma_f32 pairs; ab is scalar.
// Vertical accumulators register-rotated; first-tap overwrite (no resets).
__global__ __launch_bounds__(256) void ssim_strip_kernel(
    const float* __restrict__ in1,
    const float* __restrict__ in2,
    const float* __restrict__ win,
    double* __restrict__ partials)
{
    __shared__ v2f sh[WPB][KW][SW];   // 28160 B

    const int t = threadIdx.x;
    const int wid = t >> 6;
    const int lane = t & 63;
    const int strip = blockIdx.x * WPB + wid;
    const int x0 = strip * 64;
    const int y0 = blockIdx.y * TY;
    const int img = blockIdx.z;

    const int nx = min(64, OW - x0);     // 64, last strip 54
    const int ny = min(TY, OH - y0);     // 32, last y-strip 22

    // separable 1D gaussian; symmetric: g[j] == g[10-j] -> 6 unique splats
    v2f gp[6];
    {
        const float c = sqrtf(win[5 * KW + 5]);
        #pragma unroll
        for (int i = 0; i < 6; ++i) {
            const float w = rfl(win[i * KW + 5] / c);
            gp[i] = (v2f){w, w};
        }
    }
    #define GW(j) gp[(j) <= 5 ? (j) : 10 - (j)]

    const float maskf = (lane < nx) ? 1.f : 0.f;
    const bool stager = lane < 40;                    // 40 lanes x 2 cols = 80
    const int scol = min(x0 + 2 * lane, WW - 2);      // clamped: no OOB
    const float* b1 = in1 + (size_t)img * HH * WW;
    const float* b2 = in2 + (size_t)img * HH * WW;

    v2f* const mysh = &sh[wid][0][0];                 // slot stride = SW v2f

    v2f va, vb;
#define LOADR(q) { const int rq = min(y0 + (q), HH - 1);             \
    va = *(const v2f*)(b1 + (size_t)rq * WW + scol);                 \
    vb = *(const v2f*)(b2 + (size_t)rq * WW + scol); }
#define WRITES(slot) { if (stager)                                    \
    *(float4*)&mysh[(slot) * SW + 2 * lane] =                         \
        make_float4(va.x, vb.x, va.y, vb.y); }

    // vertical accumulators: (a,b) packed, (aa,bb) packed, ab scalar
    v2f accab[KW], accsq[KW];
    float acc4[KW];
    #pragma unroll
    for (int i = 0; i < KW; ++i) {
        accab[i] = (v2f){0.f, 0.f}; accsq[i] = (v2f){0.f, 0.f}; acc4[i] = 0.f;
    }

    double tsum = 0.0;

    LOADR(0);
    WRITES(0);

    for (int c = 0; c < 4; ++c) {        // 44 rows total, fixed
        float csum = 0.f;
        #pragma unroll
        for (int p = 0; p < KW; ++p) {
            const int yr = c * KW + p;
            LOADR(yr + 1);               // global prefetch (uniform row, clamped)

            // horizontal 11-tap conv, packed channels
            const v2f* rp = &sh[wid][p][lane];
            v2f hab = (v2f){0.f, 0.f}, hsq = (v2f){0.f, 0.f};
            float h4 = 0.f;
            #pragma unroll
            for (int j = 0; j < KW; ++j) {
                const v2f ab = rp[j];
                const v2f g = GW(j);
                const v2f gab = g * ab;                              // pk_mul
                hab = __builtin_elementwise_fma(g, ab, hab);         // pk_fma
                hsq = __builtin_elementwise_fma(gab, ab, hsq);       // pk_fma
                h4 = fmaf(gab.x, ab.y, h4);                          // scalar
            }
            // vertical accumulate: at phase p, slot j lives in register (j+p)%11;
            // weight for slot j is g[10-j]; slot 10 (reg (p+10)%11) is the
            // FIRST tap -> overwrite (no reset needed).
            #pragma unroll
            for (int r = 0; r < KW; ++r) {
                const int j = (r - p + KW) % KW;
                const v2f g = GW(10 - j);
                if (j == 10) {
                    accab[r] = g * hab;
                    accsq[r] = g * hsq;
                    acc4[r] = g.x * h4;
                } else {
                    accab[r] = __builtin_elementwise_fma(g, hab, accab[r]);
                    accsq[r] = __builtin_elementwise_fma(g, hsq, accsq[r]);
                    acc4[r] = fmaf(g.x, h4, acc4[r]);
                }
            }
            // register p completes -> output row yr-10 (uniform branch)
            if (yr >= HALO) {
                const v2f mu = accab[p];
                const v2f sq = __builtin_elementwise_fma(-mu, mu, accsq[p]);
                const float s12 = fmaf(-mu.x, mu.y, acc4[p]);
                const float den = __builtin_amdgcn_sqrtf(fabsf(sq.x)) *
                                  __builtin_amdgcn_sqrtf(fabsf(sq.y)) + C3V;
                const float s = (s12 + C3V) * __builtin_amdgcn_rcpf(den);
                const float m = ((yr - HALO) < ny) ? maskf : 0.f;
                csum = fmaf(s, m, csum);
            }

            WRITES((p + 1) % KW);        // row yr+1 -> slot p+1
        }
        tsum += (double)csum;
    }
#undef LOADR
#undef WRITES
#undef GW

    // per-wave deterministic reduction
    #pragma unroll
    for (int off = 32; off > 0; off >>= 1)
        tsum += __shfl_down(tsum, off, 64);
    if (lane == 0) {
        const int bid = (img * NBY + blockIdx.y) * NSX + strip;
        partials[bid] = tsum;
    }
}

// deterministic final reduce of the 4096 wave partials -> mean
__global__ __launch_bounds__(256) void ssim_reduce_kernel(
    const double* __restrict__ partials, float* __restrict__ out)
{
    __shared__ double sred[4];
    double s = 0.0;
    for (int i = threadIdx.x; i < NWAVE; i += 256) s += partials[i];
    #pragma unroll
    for (int off = 32; off > 0; off >>= 1)
        s += __shfl_down(s, off, 64);
    const int wid = threadIdx.x >> 6;
    const int lane = threadIdx.x & 63;
    if (lane == 0) sred[wid] = s;
    __syncthreads();
    if (threadIdx.x == 0) {
        const double total = sred[0] + sred[1] + sred[2] + sred[3];
        out[0] = (float)(total / ((double)BATCH * OH * OW));
    }
}

extern "C" void kernel_launch(void* const* d_in, const int* in_sizes, int n_in,
                              void* d_out, int out_size, void* d_ws, size_t ws_size,
                              hipStream_t stream) {
    const float* in1 = (const float*)d_in[0];
    const float* in2 = (const float*)d_in[1];
    const float* win = (const float*)d_in[2];
    float* out = (float*)d_out;
    double* partials = (double*)d_ws;   // 4096 doubles = 32 KB

    dim3 grid(NBX, NBY, BATCH);
    dim3 block(WPB * 64);
    ssim_strip_kernel<<<grid, block, 0, stream>>>(in1, in2, win, partials);
    ssim_reduce_kernel<<<1, 256, 0, stream>>>(partials, out);
}

// Round 7
// 48.219 us; speedup vs baseline: 3.5411x; 1.0064x over previous
//
#include <hip/hip_runtime.h>
#include <math.h>

#define KW 11
#define HALO 10
#define TY 32
#define BATCH 32
#define HH 512
#define WW 512
#define OH 502
#define OW 502
#define NSX 8          // 8 strips x 64 cols
#define WPB 2          // independent waves per block (no __syncthreads)
#define NBX 4
#define NBY 16
#define NWAVE (BATCH * NBY * NSX)
#define C3V 1.0e-4f
#define SW 80          // staged cols per row (64 + 16 halo), one v2f (a,b) each

typedef float v2f __attribute__((ext_vector_type(2)));

static __device__ __forceinline__ float rfl(float x) {
    return __int_as_float(__builtin_amdgcn_readfirstlane(__float_as_int(x)));
}

// 2 independent waves/block. Each wave: 64-col strip, 44 rows through an
// 11-slot wave-private LDS ring of interleaved (a,b) rows. Packed-f32 math.
// Phase body is consume-then-refill software-pipelined:
//   1) h-conv from window regs W (row yr)
//   2) ds_write row yr+1 -> slot p+1
//   3) ds_read slot p+1 -> W (latency covered by step 5)
//   4) global prefetch row yr+2 (regs)
//   5) v-conv (register-rotated) + fused epilogue
__global__ __launch_bounds__(128) void ssim_strip_kernel(
    const float* __restrict__ in1,
    const float* __restrict__ in2,
    const float* __restrict__ win,
    double* __restrict__ partials)
{
    __shared__ v2f sh[WPB][KW][SW];   // 14080 B

    const int t = threadIdx.x;
    const int wid = t >> 6;
    const int lane = t & 63;
    const int strip = blockIdx.x * WPB + wid;
    const int x0 = strip * 64;
    const int y0 = blockIdx.y * TY;
    const int img = blockIdx.z;

    const int nx = min(64, OW - x0);     // 64, last strip 54
    const int ny = min(TY, OH - y0);     // 32, last y-strip 22

    // separable 1D gaussian; symmetric: g[j] == g[10-j] -> 6 unique splats
    v2f gp[6];
    {
        const float c = sqrtf(win[5 * KW + 5]);
        #pragma unroll
        for (int i = 0; i < 6; ++i) {
            const float w = rfl(win[i * KW + 5] / c);
            gp[i] = (v2f){w, w};
        }
    }
    #define GW(j) gp[(j) <= 5 ? (j) : 10 - (j)]

    const float maskf = (lane < nx) ? 1.f : 0.f;
    const bool stager = lane < 40;                    // 40 lanes x 2 cols = 80
    const int scol = min(x0 + 2 * lane, WW - 2);      // clamped: no OOB
    const float* b1 = in1 + (size_t)img * HH * WW;
    const float* b2 = in2 + (size_t)img * HH * WW;

    v2f* const mysh = &sh[wid][0][0];                 // slot stride = SW v2f

    v2f va, vb;
#define LOADR(q) { const int rq = min(y0 + (q), HH - 1);             \
    va = *(const v2f*)(b1 + (size_t)rq * WW + scol);                 \
    vb = *(const v2f*)(b2 + (size_t)rq * WW + scol); }
#define WRITES(slot) { if (stager)                                    \
    *(float4*)&mysh[(slot) * SW + 2 * lane] =                         \
        make_float4(va.x, vb.x, va.y, vb.y); }
#define RDWIN(slot) { _Pragma("unroll")                               \
    for (int j = 0; j < KW; ++j) W[j] = mysh[(slot) * SW + lane + j]; }

    // vertical accumulators: (a,b) packed, (aa,bb) packed, ab scalar
    v2f accab[KW], accsq[KW];
    float acc4[KW];
    #pragma unroll
    for (int i = 0; i < KW; ++i) {
        accab[i] = (v2f){0.f, 0.f}; accsq[i] = (v2f){0.f, 0.f}; acc4[i] = 0.f;
    }

    v2f W[KW];
    double tsum = 0.0;

    // prologue: row 0 staged + window loaded; row 1 in staging regs
    LOADR(0);
    WRITES(0);
    RDWIN(0);
    LOADR(1);

    for (int c = 0; c < 4; ++c) {        // 44 rows total, fixed
        float csum = 0.f;
        #pragma unroll
        for (int p = 0; p < KW; ++p) {
            const int yr = c * KW + p;

            // 1) horizontal 11-tap conv from W (row yr), packed channels
            v2f hab = (v2f){0.f, 0.f}, hsq = (v2f){0.f, 0.f};
            float h4 = 0.f;
            #pragma unroll
            for (int j = 0; j < KW; ++j) {
                const v2f ab = W[j];
                const v2f g = GW(j);
                const v2f gab = g * ab;                              // pk_mul
                hab = __builtin_elementwise_fma(g, ab, hab);         // pk_fma
                hsq = __builtin_elementwise_fma(gab, ab, hsq);       // pk_fma
                h4 = fmaf(gab.x, ab.y, h4);                          // scalar
            }

            // 2) stage row yr+1 into slot p+1 (data from LOADR at prev phase)
            WRITES((p + 1) % KW);
            // 3) refill W with row yr+1's window (latency hidden by step 5)
            RDWIN((p + 1) % KW);
            // 4) global prefetch row yr+2
            LOADR(yr + 2);

            // 5) vertical accumulate: at phase p, slot j lives in register
            //    (j+p)%11; slot 10 is the first tap -> overwrite (no reset)
            #pragma unroll
            for (int r = 0; r < KW; ++r) {
                const int j = (r - p + KW) % KW;
                const v2f g = GW(10 - j);
                if (j == 10) {
                    accab[r] = g * hab;
                    accsq[r] = g * hsq;
                    acc4[r] = g.x * h4;
                } else {
                    accab[r] = __builtin_elementwise_fma(g, hab, accab[r]);
                    accsq[r] = __builtin_elementwise_fma(g, hsq, accsq[r]);
                    acc4[r] = fmaf(g.x, h4, acc4[r]);
                }
            }
            // register p completes -> output row yr-10 (uniform branch)
            if (yr >= HALO) {
                const v2f mu = accab[p];
                const v2f sq = __builtin_elementwise_fma(-mu, mu, accsq[p]);
                const float s12 = fmaf(-mu.x, mu.y, acc4[p]);
                const float den = __builtin_amdgcn_sqrtf(fabsf(sq.x * sq.y)) + C3V;
                const float s = (s12 + C3V) * __builtin_amdgcn_rcpf(den);
                const float m = ((yr - HALO) < ny) ? maskf : 0.f;
                csum = fmaf(s, m, csum);
            }
        }
        tsum += (double)csum;
    }
#undef LOADR
#undef WRITES
#undef RDWIN
#undef GW

    // per-wave deterministic reduction
    #pragma unroll
    for (int off = 32; off > 0; off >>= 1)
        tsum += __shfl_down(tsum, off, 64);
    if (lane == 0) {
        const int bid = (img * NBY + blockIdx.y) * NSX + strip;
        partials[bid] = tsum;
    }
}

// deterministic final reduce of the 4096 wave partials -> mean
__global__ __launch_bounds__(256) void ssim_reduce_kernel(
    const double* __restrict__ partials, float* __restrict__ out)
{
    __shared__ double sred[4];
    double s = 0.0;
    for (int i = threadIdx.x; i < NWAVE; i += 256) s += partials[i];
    #pragma unroll
    for (int off = 32; off > 0; off >>= 1)
        s += __shfl_down(s, off, 64);
    const int wid = threadIdx.x >> 6;
    const int lane = threadIdx.x & 63;
    if (lane == 0) sred[wid] = s;
    __syncthreads();
    if (threadIdx.x == 0) {
        const double total = sred[0] + sred[1] + sred[2] + sred[3];
        out[0] = (float)(total / ((double)BATCH * OH * OW));
    }
}

extern "C" void kernel_launch(void* const* d_in, const int* in_sizes, int n_in,
                              void* d_out, int out_size, void* d_ws, size_t ws_size,
                              hipStream_t stream) {
    const float* in1 = (const float*)d_in[0];
    const float* in2 = (const float*)d_in[1];
    const float* win = (const float*)d_in[2];
    float* out = (float*)d_out;
    double* partials = (double*)d_ws;   // 4096 doubles = 32 KB

    dim3 grid(NBX, NBY, BATCH);
    dim3 block(WPB * 64);
    ssim_strip_kernel<<<grid, block, 0, stream>>>(in1, in2, win, partials);
    ssim_reduce_kernel<<<1, 256, 0, stream>>>(partials, out);
}